// Round 9
// baseline (137.916 us; speedup 1.0000x reference)
//
#include <hip/hip_runtime.h>

#define NCTX 2048
#define NH   8
#define WD   32
#define NTOK 512

static constexpr float SCALE = 0.04419417382415922f; // 1/sqrt(512)

// Forced software pipeline: asm global_load_dwordx4 (cannot be sunk by the
// compiler) + counted s_waitcnt vmcnt(N) followed by sched_barrier(0) (rule
// #18: the barrier stops the machine scheduler from hoisting the consuming
// VALU above the wait; tied "+v" operands do NOT compile on hipcc).
#define ISSUE8(qp, vp, a0,a1,a2,a3,a4,a5,a6,a7)            \
  asm volatile(                                            \
    "global_load_dwordx4 %0, %8, off\n\t"                  \
    "global_load_dwordx4 %1, %8, off offset:16\n\t"        \
    "global_load_dwordx4 %2, %8, off offset:32\n\t"        \
    "global_load_dwordx4 %3, %8, off offset:48\n\t"        \
    "global_load_dwordx4 %4, %9, off\n\t"                  \
    "global_load_dwordx4 %5, %9, off offset:16\n\t"        \
    "global_load_dwordx4 %6, %9, off offset:32\n\t"        \
    "global_load_dwordx4 %7, %9, off offset:48\n\t"        \
    : "=&v"(a0),"=&v"(a1),"=&v"(a2),"=&v"(a3),             \
      "=&v"(a4),"=&v"(a5),"=&v"(a6),"=&v"(a7)              \
    : "v"(qp), "v"(vp))

#define WAITV(N)                                           \
  do {                                                     \
    asm volatile("s_waitcnt vmcnt(" #N ")" ::: "memory");  \
    __builtin_amdgcn_sched_barrier(0);                     \
  } while (0)

#define BODY(q0,q1,q2,q3, v0,v1,v2,v3)                                      \
  do {                                                                      \
    float d0, d1, d2, d3;                                                   \
    d0  = fabsf(q0.x - kg[ 0]); d1  = fabsf(q0.y - kg[ 1]);                 \
    d2  = fabsf(q0.z - kg[ 2]); d3  = fabsf(q0.w - kg[ 3]);                 \
    d0 += fabsf(q1.x - kg[ 4]); d1 += fabsf(q1.y - kg[ 5]);                 \
    d2 += fabsf(q1.z - kg[ 6]); d3 += fabsf(q1.w - kg[ 7]);                 \
    d0 += fabsf(q2.x - kg[ 8]); d1 += fabsf(q2.y - kg[ 9]);                 \
    d2 += fabsf(q2.z - kg[10]); d3 += fabsf(q2.w - kg[11]);                 \
    d0 += fabsf(q3.x - kg[12]); d1 += fabsf(q3.y - kg[13]);                 \
    d2 += fabsf(q3.z - kg[14]); d3 += fabsf(q3.w - kg[15]);                 \
    float d = (d0 + d1) + (d2 + d3);                                        \
    d += __shfl_xor(d, 32, 64);       /* combine the two half-rows */       \
    const float p = __expf(-SCALE * d); /* d in [0,~350]: no shift */       \
    l += p;                                                                 \
    acc[ 0] = fmaf(p, v0.x, acc[ 0]); acc[ 1] = fmaf(p, v0.y, acc[ 1]);     \
    acc[ 2] = fmaf(p, v0.z, acc[ 2]); acc[ 3] = fmaf(p, v0.w, acc[ 3]);     \
    acc[ 4] = fmaf(p, v1.x, acc[ 4]); acc[ 5] = fmaf(p, v1.y, acc[ 5]);     \
    acc[ 6] = fmaf(p, v1.z, acc[ 6]); acc[ 7] = fmaf(p, v1.w, acc[ 7]);     \
    acc[ 8] = fmaf(p, v2.x, acc[ 8]); acc[ 9] = fmaf(p, v2.y, acc[ 9]);     \
    acc[10] = fmaf(p, v2.z, acc[10]); acc[11] = fmaf(p, v2.w, acc[11]);     \
    acc[12] = fmaf(p, v3.x, acc[12]); acc[13] = fmaf(p, v3.y, acc[13]);     \
    acc[14] = fmaf(p, v3.z, acc[14]); acc[15] = fmaf(p, v3.w, acc[15]);     \
  } while (0)

// Block = 512 thr (8 waves) = one (plane, 32-row group, j-span of 512/S).
// lane = whalf*32 + r: lane owns HALF a row (kg[16], acc[16]).
// No LDS for q/v: bodies read wave-broadcast rows straight from global
// (L1/L2-resident) via asm-pinned loads, depth-2 ping-pong with vmcnt(8).
template<int S>
__global__ __launch_bounds__(512, 4) void l1attn_main(
    const float* __restrict__ q, const float* __restrict__ k,
    const float* __restrict__ v, const int* __restrict__ indx,
    float* __restrict__ dst /* S>1 ? ws : out */) {
  constexpr int JSPAN = NTOK / S;       // tokens this block accumulates
  constexpr int JPW   = JSPAN / 8;      // j's per wave (>= 4, even)
  __shared__ int   indxS[NTOK];
  __shared__ float accS[32 * 33];       // [row][w] stride 33
  __shared__ float lS[32];

  const int tid = threadIdx.x;
  const int bid = blockIdx.x;
  const int pr  = bid / S;              // plane*16 + rowgroup   [0,256)
  const int jw  = bid % S;              // j-span index
  const int plane = pr >> 4;            // b*8 + h
  const int rg    = pr & 15;
  const int b     = plane >> 3;
  const int h     = plane & 7;

  indxS[tid] = indx[tid];
  for (int i = tid; i < 32 * 33; i += 512) accS[i] = 0.f;
  if (tid < 32) lS[tid] = 0.f;
  __syncthreads();

  const int lane  = tid & 63;
  const int wave  = __builtin_amdgcn_readfirstlane(tid >> 6); // 0..7
  const int r     = lane & 31;          // row within group
  const int whalf = lane >> 5;          // which 16 of the 32 w's

  const float* qb = q + ((size_t)b * NCTX * NH + h) * WD + whalf * 16;
  const float* vb = v + ((size_t)b * NCTX * NH + h) * WD + whalf * 16;
  const float* kb = k + ((size_t)b * NCTX * NH + h) * WD + whalf * 16;

  // per-lane half K-row (output row s keys on k per the einsum relabeling)
  float kg[16];
  {
    const int s = rg * 32 + r;
    const float4* kr = (const float4*)(kb + (size_t)indxS[s] * (NH * WD));
#pragma unroll
    for (int i = 0; i < 4; ++i) {
      float4 t = kr[i];
      kg[4*i+0] = t.x; kg[4*i+1] = t.y; kg[4*i+2] = t.z; kg[4*i+3] = t.w;
    }
  }

  float acc[16];
#pragma unroll
  for (int i = 0; i < 16; ++i) acc[i] = 0.f;
  float l = 0.f;

  const int jb = jw * JSPAN + wave * JPW;

  float4 Aq0, Aq1, Aq2, Aq3, Av0, Av1, Av2, Av3;
  float4 Bq0, Bq1, Bq2, Bq3, Bv0, Bv1, Bv2, Bv3;

  {
    const int tok0 = indxS[jb];
    ISSUE8(qb + (size_t)tok0 * 256, vb + (size_t)tok0 * 256,
           Aq0, Aq1, Aq2, Aq3, Av0, Av1, Av2, Av3);
  }

  // steady state: 8 or 16 loads in flight; last pair peeled (no dangling loads)
  for (int jj = 0; jj < JPW - 2; jj += 2) {
    {
      const int t1 = indxS[jb + jj + 1];
      ISSUE8(qb + (size_t)t1 * 256, vb + (size_t)t1 * 256,
             Bq0, Bq1, Bq2, Bq3, Bv0, Bv1, Bv2, Bv3);
      WAITV(8);
      BODY(Aq0, Aq1, Aq2, Aq3, Av0, Av1, Av2, Av3);
    }
    {
      const int t2 = indxS[jb + jj + 2];
      ISSUE8(qb + (size_t)t2 * 256, vb + (size_t)t2 * 256,
             Aq0, Aq1, Aq2, Aq3, Av0, Av1, Av2, Av3);
      WAITV(8);
      BODY(Bq0, Bq1, Bq2, Bq3, Bv0, Bv1, Bv2, Bv3);
    }
  }
  {
    const int t1 = indxS[jb + JPW - 1];
    ISSUE8(qb + (size_t)t1 * 256, vb + (size_t)t1 * 256,
           Bq0, Bq1, Bq2, Bq3, Bv0, Bv1, Bv2, Bv3);
    WAITV(8);
    BODY(Aq0, Aq1, Aq2, Aq3, Av0, Av1, Av2, Av3);
    WAITV(0);
    BODY(Bq0, Bq1, Bq2, Bq3, Bv0, Bv1, Bv2, Bv3);
  }

  // combine the 8 wave partials (same 32 rows) in LDS
#pragma unroll
  for (int w = 0; w < 16; ++w)
    atomicAdd(&accS[r * 33 + whalf * 16 + w], acc[w]);
  if (whalf == 0) atomicAdd(&lS[r], l);
  __syncthreads();

  if (S > 1) {
    float* wsB = dst + (size_t)bid * 1056;          // 32*32 acc + 32 l
    for (int i = tid; i < 1024; i += 512)
      wsB[i] = accS[(i >> 5) * 33 + (i & 31)];
    if (tid < 32) wsB[1024 + tid] = lS[tid];
  } else {
    for (int i = tid; i < 1024; i += 512) {
      const int rr = i >> 5, w = i & 31;
      dst[(((size_t)b * NTOK + rg * 32 + rr) * NH + h) * WD + w] =
          accS[rr * 33 + w] / lS[rr];
    }
  }
}

template<int S>
__global__ __launch_bounds__(1024) void l1attn_combine(
    const float* __restrict__ ws, float* __restrict__ out) {
  const int gid = blockIdx.x * 1024 + threadIdx.x;  // [0, 262144)
  const int w  = gid & 31;
  const int r  = (gid >> 5) & 31;
  const int pr = gid >> 10;                         // [0, 256)
  const float* base = ws + (size_t)pr * S * 1056;
  float a = 0.f, ls = 0.f;
#pragma unroll
  for (int jwi = 0; jwi < S; ++jwi) {
    a  += base[jwi * 1056 + r * 32 + w];
    ls += base[jwi * 1056 + 1024 + r];
  }
  const int plane = pr >> 4, rg = pr & 15;
  const int b = plane >> 3, h = plane & 7;
  out[(((size_t)b * NTOK + rg * 32 + r) * NH + h) * WD + w] = a / ls;
}

extern "C" void kernel_launch(void* const* d_in, const int* in_sizes, int n_in,
                              void* d_out, int out_size, void* d_ws, size_t ws_size,
                              hipStream_t stream) {
  const float* q    = (const float*)d_in[0];
  const float* k    = (const float*)d_in[1];
  const float* v    = (const float*)d_in[2];
  const int*   indx = (const int*)d_in[3];
  float*       out  = (float*)d_out;

  const size_t need4 = (size_t)1024 * 1056 * sizeof(float);  // 4.3 MB
  const size_t need2 = (size_t)512  * 1056 * sizeof(float);  // 2.2 MB
  if (ws_size >= need4) {
    hipLaunchKernelGGL((l1attn_main<4>), dim3(1024), dim3(512), 0, stream,
                       q, k, v, indx, (float*)d_ws);
    hipLaunchKernelGGL((l1attn_combine<4>), dim3(256), dim3(1024), 0, stream,
                       (const float*)d_ws, out);
  } else if (ws_size >= need2) {
    hipLaunchKernelGGL((l1attn_main<2>), dim3(512), dim3(512), 0, stream,
                       q, k, v, indx, (float*)d_ws);
    hipLaunchKernelGGL((l1attn_combine<2>), dim3(256), dim3(1024), 0, stream,
                       (const float*)d_ws, out);
  } else {
    hipLaunchKernelGGL((l1attn_main<1>), dim3(256), dim3(512), 0, stream,
                       q, k, v, indx, out);
  }
}